// Round 12
// baseline (433.415 us; speedup 1.0000x reference)
//
#include <hip/hip_runtime.h>
#include <hip/hip_fp16.h>

#define DD 64
#define NB 256          // buckets (one per passC block); requires n <= 65536
#define GB 128          // blocks for histA/passB

// ---------------------------------------------------------------------------
// Inline int64-vs-int32 detection: first 128 odd u32 words all zero <=> int64.
__device__ __forceinline__ int detect_is64(const unsigned int* p, int E,
                                           int tid, int* sflag) {
  if (tid == 0) *sflag = 1;
  __syncthreads();
  int lim = E < 128 ? E : 128;
  if (tid < lim && p[2 * tid + 1] != 0u) *sflag = 0;
  __syncthreads();
  return *sflag;
}

// ---- histA: per-(block,bucket) histogram of dst ---------------------------
__global__ __launch_bounds__(256) void histA_kernel(
    const void* __restrict__ eidx, int E, int chunk,
    int* __restrict__ histPB) {
  __shared__ int h[NB];
  __shared__ int sflag;
  int tid = threadIdx.x;
  int is64 = detect_is64((const unsigned int*)eidx, E, tid, &sflag);
  h[tid] = 0;
  __syncthreads();
  int seg = (E + GB - 1) / GB;
  int e0 = blockIdx.x * seg;
  int e1 = min(e0 + seg, E);
  for (int e = e0 + tid; e < e1; e += 256) {
    int d;
    if (is64) d = (int)((const long long*)eidx)[e + E];
    else      d = ((const int*)eidx)[e + E];
    atomicAdd(&h[d / chunk], 1);
  }
  __syncthreads();
  histPB[blockIdx.x * NB + tid] = h[tid];
}

// ---- scanB1: per-bucket scan over the GB block counts ---------------------
__global__ __launch_bounds__(GB) void scanB1_kernel(
    const int* __restrict__ histPB, int* __restrict__ localpre,
    int* __restrict__ tot) {
  __shared__ int s[GB];
  int b = blockIdx.x;        // bucket
  int t = threadIdx.x;       // source block
  int v = histPB[t * NB + b];
  s[t] = v;
  __syncthreads();
  for (int off = 1; off < GB; off <<= 1) {
    int tv = (t >= off) ? s[t - off] : 0;
    __syncthreads();
    s[t] += tv;
    __syncthreads();
  }
  localpre[b * GB + t] = s[t] - v;   // exclusive prefix within bucket
  if (t == GB - 1) tot[b] = s[t];
}

// ---- scanB2: scan bucket totals -> bucketBase, csrBase, offs[n] -----------
__global__ __launch_bounds__(NB) void scanB2_kernel(
    const int* __restrict__ tot, int* __restrict__ bucketBase,
    int* __restrict__ csrBase, int* __restrict__ offs, int n, int chunk) {
  __shared__ int sc[NB];
  int b = threadIdx.x;
  int v = tot[b];
  sc[b] = v;
  __syncthreads();
  for (int off = 1; off < NB; off <<= 1) {
    int t = (b >= off) ? sc[b - off] : 0;
    __syncthreads();
    sc[b] += t;
    __syncthreads();
  }
  int excl = sc[b] - v;
  bucketBase[b] = excl;
  if (b == NB - 1) {
    bucketBase[NB] = excl + v;       // == E
    offs[n] = excl + v + n;          // == E + n
  }
  int dpre = b * chunk; if (dpre > n) dpre = n;
  csrBase[b] = excl + dpre;
}

// ---- passB: bucketed scatter of packed records (src<<16 | local_dst) ------
__global__ __launch_bounds__(256) void passB_kernel(
    const void* __restrict__ eidx, int E, int chunk,
    const int* __restrict__ bucketBase, const int* __restrict__ localpre,
    unsigned int* __restrict__ rec) {
  __shared__ int cur[NB];
  __shared__ int sflag;
  int tid = threadIdx.x;
  int is64 = detect_is64((const unsigned int*)eidx, E, tid, &sflag);
  cur[tid] = bucketBase[tid] + localpre[tid * GB + blockIdx.x];
  __syncthreads();
  int seg = (E + GB - 1) / GB;
  int e0 = blockIdx.x * seg;
  int e1 = min(e0 + seg, E);
  for (int e = e0 + tid; e < e1; e += 256) {
    int s, d;
    if (is64) {
      const long long* p = (const long long*)eidx;
      s = (int)p[e];
      d = (int)p[e + E];
    } else {
      const int* p = (const int*)eidx;
      s = p[e];
      d = p[e + E];
    }
    int b = d / chunk;
    int ld = d - b * chunk;
    int pos = atomicAdd(&cur[b], 1);
    rec[pos] = ((unsigned int)s << 16) | (unsigned int)ld;
  }
}

// ---- passC: per-bucket CSR finalize (offs, dinv, col) ---------------------
__global__ __launch_bounds__(256) void passC_kernel(
    const unsigned int* __restrict__ rec, const int* __restrict__ bucketBase,
    const int* __restrict__ csrBase, int* __restrict__ offs,
    float* __restrict__ dinv, int* __restrict__ col, int n, int chunk) {
  int b = blockIdx.x;
  int tid = threadIdx.x;
  int d0 = b * chunk;
  if (d0 >= n) return;
  int nd = min(chunk, n - d0);
  int jb0 = bucketBase[b], jb1 = bucketBase[b + 1];
  int cb = csrBase[b];

  __shared__ int hist[NB];
  __shared__ int sc[NB];
  __shared__ int cursor[NB];
  hist[tid] = (tid < nd) ? 1 : 0;   // self-loop seed
  __syncthreads();
  for (int j = jb0 + tid; j < jb1; j += 256)
    atomicAdd(&hist[rec[j] & 0xFFFFu], 1);
  __syncthreads();
  int deg = hist[tid];
  sc[tid] = deg;
  __syncthreads();
  for (int off = 1; off < 256; off <<= 1) {
    int t = (tid >= off) ? sc[tid - off] : 0;
    __syncthreads();
    sc[tid] += t;
    __syncthreads();
  }
  int loc = sc[tid] - deg;          // exclusive prefix
  if (tid < nd) {
    offs[d0 + tid] = cb + loc;
    dinv[d0 + tid] = rsqrtf((float)deg);
    col[cb + loc] = d0 + tid;       // self-loop first
  }
  cursor[tid] = loc + 1;
  __syncthreads();
  for (int j = jb0 + tid; j < jb1; j += 256) {
    unsigned int r = rec[j];
    int p = atomicAdd(&cursor[(int)(r & 0xFFFFu)], 1);
    col[cb + p] = (int)(r >> 16);
  }
}

// ---- fused layer0+transform1: T16 = dinv * (relu(x@Win + bin) @ W1) -------
__global__ __launch_bounds__(256) void gemm01_kernel(
    const float* __restrict__ X, const float* __restrict__ Win,
    const float* __restrict__ bin, const float* __restrict__ W1,
    const float* __restrict__ dinv, __half* __restrict__ T16, int n) {
  __shared__ float Ws[64][68];
  __shared__ float Hs[64][68];
  int tid = threadIdx.x;
  int row0 = blockIdx.x * 64;

  for (int i = tid; i < 1024; i += 256) {
    int r = i >> 4, c = (i & 15) << 2;
    *reinterpret_cast<float4*>(&Ws[r][c]) = ((const float4*)Win)[i];
    float4 hv = make_float4(0.f, 0.f, 0.f, 0.f);
    if (row0 + r < n)
      hv = *reinterpret_cast<const float4*>(X + (size_t)(row0 + r) * DD + c);
    *reinterpret_cast<float4*>(&Hs[r][c]) = hv;
  }
  __syncthreads();

  int tr = tid >> 4, tc = tid & 15;
  int r0 = tr << 2, c0 = tc << 2;

  float acc[4][4];
#pragma unroll
  for (int i = 0; i < 4; ++i)
#pragma unroll
    for (int j = 0; j < 4; ++j) acc[i][j] = 0.f;

#pragma unroll
  for (int k = 0; k < 64; ++k) {
    float h0 = Hs[r0 + 0][k], h1 = Hs[r0 + 1][k];
    float h2 = Hs[r0 + 2][k], h3 = Hs[r0 + 3][k];
    float4 wv = *reinterpret_cast<const float4*>(&Ws[k][c0]);
    acc[0][0] = fmaf(h0, wv.x, acc[0][0]); acc[0][1] = fmaf(h0, wv.y, acc[0][1]);
    acc[0][2] = fmaf(h0, wv.z, acc[0][2]); acc[0][3] = fmaf(h0, wv.w, acc[0][3]);
    acc[1][0] = fmaf(h1, wv.x, acc[1][0]); acc[1][1] = fmaf(h1, wv.y, acc[1][1]);
    acc[1][2] = fmaf(h1, wv.z, acc[1][2]); acc[1][3] = fmaf(h1, wv.w, acc[1][3]);
    acc[2][0] = fmaf(h2, wv.x, acc[2][0]); acc[2][1] = fmaf(h2, wv.y, acc[2][1]);
    acc[2][2] = fmaf(h2, wv.z, acc[2][2]); acc[2][3] = fmaf(h2, wv.w, acc[2][3]);
    acc[3][0] = fmaf(h3, wv.x, acc[3][0]); acc[3][1] = fmaf(h3, wv.y, acc[3][1]);
    acc[3][2] = fmaf(h3, wv.z, acc[3][2]); acc[3][3] = fmaf(h3, wv.w, acc[3][3]);
  }

  // h = relu(acc + bin)
  float4 bv = *reinterpret_cast<const float4*>(bin + c0);
#pragma unroll
  for (int i = 0; i < 4; ++i) {
    acc[i][0] = fmaxf(acc[i][0] + bv.x, 0.f);
    acc[i][1] = fmaxf(acc[i][1] + bv.y, 0.f);
    acc[i][2] = fmaxf(acc[i][2] + bv.z, 0.f);
    acc[i][3] = fmaxf(acc[i][3] + bv.w, 0.f);
  }
  __syncthreads();              // everyone done reading Hs/Ws

  // write h tile back into Hs; restage Ws = W1
#pragma unroll
  for (int i = 0; i < 4; ++i)
    *reinterpret_cast<float4*>(&Hs[r0 + i][c0]) =
        make_float4(acc[i][0], acc[i][1], acc[i][2], acc[i][3]);
  for (int i = tid; i < 1024; i += 256) {
    int r = i >> 4, c = (i & 15) << 2;
    *reinterpret_cast<float4*>(&Ws[r][c]) = ((const float4*)W1)[i];
  }
  __syncthreads();

#pragma unroll
  for (int i = 0; i < 4; ++i)
#pragma unroll
    for (int j = 0; j < 4; ++j) acc[i][j] = 0.f;

#pragma unroll
  for (int k = 0; k < 64; ++k) {
    float h0 = Hs[r0 + 0][k], h1 = Hs[r0 + 1][k];
    float h2 = Hs[r0 + 2][k], h3 = Hs[r0 + 3][k];
    float4 wv = *reinterpret_cast<const float4*>(&Ws[k][c0]);
    acc[0][0] = fmaf(h0, wv.x, acc[0][0]); acc[0][1] = fmaf(h0, wv.y, acc[0][1]);
    acc[0][2] = fmaf(h0, wv.z, acc[0][2]); acc[0][3] = fmaf(h0, wv.w, acc[0][3]);
    acc[1][0] = fmaf(h1, wv.x, acc[1][0]); acc[1][1] = fmaf(h1, wv.y, acc[1][1]);
    acc[1][2] = fmaf(h1, wv.z, acc[1][2]); acc[1][3] = fmaf(h1, wv.w, acc[1][3]);
    acc[2][0] = fmaf(h2, wv.x, acc[2][0]); acc[2][1] = fmaf(h2, wv.y, acc[2][1]);
    acc[2][2] = fmaf(h2, wv.z, acc[2][2]); acc[2][3] = fmaf(h2, wv.w, acc[2][3]);
    acc[3][0] = fmaf(h3, wv.x, acc[3][0]); acc[3][1] = fmaf(h3, wv.y, acc[3][1]);
    acc[3][2] = fmaf(h3, wv.z, acc[3][2]); acc[3][3] = fmaf(h3, wv.w, acc[3][3]);
  }

#pragma unroll
  for (int i = 0; i < 4; ++i) {
    long long row = (long long)row0 + r0 + i;
    if (row >= n) break;
    float dv = dinv[row];
    __half2 p01 = __floats2half2_rn(acc[i][0] * dv, acc[i][1] * dv);
    __half2 p23 = __floats2half2_rn(acc[i][2] * dv, acc[i][3] * dv);
    uint2 u;
    u.x = *reinterpret_cast<unsigned int*>(&p01);
    u.y = *reinterpret_cast<unsigned int*>(&p23);
    *reinterpret_cast<uint2*>(T16 + (size_t)row * DD + c0) = u;
  }
}

// ---- shared gather helper -------------------------------------------------
__device__ __forceinline__ void acc8(float* acc, uint4 u) {
  __half2 h0 = *reinterpret_cast<__half2*>(&u.x);
  __half2 h1 = *reinterpret_cast<__half2*>(&u.y);
  __half2 h2 = *reinterpret_cast<__half2*>(&u.z);
  __half2 h3 = *reinterpret_cast<__half2*>(&u.w);
  float2 f0 = __half22float2(h0);
  float2 f1 = __half22float2(h1);
  float2 f2 = __half22float2(h2);
  float2 f3 = __half22float2(h3);
  acc[0] += f0.x; acc[1] += f0.y;
  acc[2] += f1.x; acc[3] += f1.y;
  acc[4] += f2.x; acc[5] += f2.y;
  acc[6] += f3.x; acc[7] += f3.y;
}

// gather one node's neighbor-sum into acc[8] (per-lane slice s, group g)
__device__ __forceinline__ void gather_node(
    const __half* __restrict__ Ts, const int* __restrict__ col,
    int j0, int deg, int lane, int g, float* acc) {
#pragma unroll
  for (int k = 0; k < 8; ++k) acc[k] = 0.f;
  for (int base = 0; base < deg; base += 64) {
    int idx = base + lane;
    int c_local = (idx < deg) ? col[j0 + idx] : -1;
    int rem = deg - base; if (rem > 64) rem = 64;
    int nr = (rem + 7) >> 3;
    int t = 0;
    for (; t + 4 <= nr; t += 4) {
      int i = t * 8 + g;
      int c0 = __shfl(c_local, i, 64);
      int c1 = __shfl(c_local, i + 8, 64);
      int c2 = __shfl(c_local, i + 16, 64);
      int c3 = __shfl(c_local, i + 24, 64);
      uint4 u0 = *reinterpret_cast<const uint4*>(Ts + (size_t)c0 * DD);
      uint4 u1 = *reinterpret_cast<const uint4*>(Ts + (size_t)c1 * DD);
      uint4 u2 = *reinterpret_cast<const uint4*>(Ts + (size_t)c2 * DD);
      if (c3 >= 0) {
        uint4 u3 = *reinterpret_cast<const uint4*>(Ts + (size_t)c3 * DD);
        acc8(acc, u3);
      }
      acc8(acc, u0);
      acc8(acc, u1);
      acc8(acc, u2);
    }
    for (; t < nr; ++t) {
      int i = t * 8 + g;
      int c = __shfl(c_local, i, 64);
      if (c >= 0) {
        uint4 u = *reinterpret_cast<const uint4*>(Ts + (size_t)c * DD);
        acc8(acc, u);
      }
    }
  }
#pragma unroll
  for (int m = 8; m <= 32; m <<= 1) {
#pragma unroll
    for (int k = 0; k < 8; ++k)
      acc[k] += __shfl_xor(acc[k], m, 64);
  }
}

// ---- fused aggregate + next transform -------------------------------------
// Tout = (dinv (*) relu(dinv*agg(Tin) + b)) @ Wnext, 64 rows per block.
__global__ __launch_bounds__(512) void agg_gemm_kernel(
    const __half* __restrict__ Tin, const int* __restrict__ offs,
    const int* __restrict__ col, const float* __restrict__ dinv,
    const float* __restrict__ bias, const float* __restrict__ Wnext,
    __half* __restrict__ Tout, int n) {
  __shared__ float Hs[64][68];
  __shared__ float Ws[64][68];
  int tid = threadIdx.x;
  int row0 = blockIdx.x * 64;

  for (int i = tid; i < 1024; i += 512) {
    int r = i >> 4, c = (i & 15) << 2;
    *reinterpret_cast<float4*>(&Ws[r][c]) = ((const float4*)Wnext)[i];
  }

  int lane = tid & 63;
  int w = tid >> 6;              // wave 0..7
  int g = lane >> 3, s = lane & 7;
  const __half* Ts = Tin + s * 8;
  float4 blo = *reinterpret_cast<const float4*>(bias + s * 8);
  float4 bhi = *reinterpret_cast<const float4*>(bias + s * 8 + 4);

  // phase A: each wave aggregates 8 nodes -> q rows in Hs
  for (int i = 0; i < 8; ++i) {
    int lrow = w * 8 + i;
    int node = row0 + lrow;
    if (node < n) {
      int j0 = offs[node], j1 = offs[node + 1];
      float acc[8];
      gather_node(Ts, col, j0, j1 - j0, lane, g, acc);
      if (g == 0) {
        float dv = dinv[node];
        float v0 = fmaxf(fmaf(acc[0], dv, blo.x), 0.f) * dv;
        float v1 = fmaxf(fmaf(acc[1], dv, blo.y), 0.f) * dv;
        float v2 = fmaxf(fmaf(acc[2], dv, blo.z), 0.f) * dv;
        float v3 = fmaxf(fmaf(acc[3], dv, blo.w), 0.f) * dv;
        float v4 = fmaxf(fmaf(acc[4], dv, bhi.x), 0.f) * dv;
        float v5 = fmaxf(fmaf(acc[5], dv, bhi.y), 0.f) * dv;
        float v6 = fmaxf(fmaf(acc[6], dv, bhi.z), 0.f) * dv;
        float v7 = fmaxf(fmaf(acc[7], dv, bhi.w), 0.f) * dv;
        *reinterpret_cast<float4*>(&Hs[lrow][s * 8]) =
            make_float4(v0, v1, v2, v3);
        *reinterpret_cast<float4*>(&Hs[lrow][s * 8 + 4]) =
            make_float4(v4, v5, v6, v7);
      }
    } else if (g == 0) {
      *reinterpret_cast<float4*>(&Hs[lrow][s * 8]) =
          make_float4(0.f, 0.f, 0.f, 0.f);
      *reinterpret_cast<float4*>(&Hs[lrow][s * 8 + 4]) =
          make_float4(0.f, 0.f, 0.f, 0.f);
    }
  }
  __syncthreads();

  // phase B: tile GEMM  Tout[row0+.., :] = Hs @ Ws  (fp16 out, no epilogue)
  int tr = tid >> 4;             // 0..31 -> 2 rows each
  int tc = tid & 15;             // 0..15 -> 4 cols each
  int r0 = tr << 1, c0 = tc << 2;
  float a0[4] = {0.f, 0.f, 0.f, 0.f};
  float a1[4] = {0.f, 0.f, 0.f, 0.f};
#pragma unroll
  for (int k = 0; k < 64; ++k) {
    float h0 = Hs[r0 + 0][k];
    float h1 = Hs[r0 + 1][k];
    float4 wv = *reinterpret_cast<const float4*>(&Ws[k][c0]);
    a0[0] = fmaf(h0, wv.x, a0[0]); a0[1] = fmaf(h0, wv.y, a0[1]);
    a0[2] = fmaf(h0, wv.z, a0[2]); a0[3] = fmaf(h0, wv.w, a0[3]);
    a1[0] = fmaf(h1, wv.x, a1[0]); a1[1] = fmaf(h1, wv.y, a1[1]);
    a1[2] = fmaf(h1, wv.z, a1[2]); a1[3] = fmaf(h1, wv.w, a1[3]);
  }
  long long rowA = (long long)row0 + r0;
  if (rowA < n) {
    __half2 p01 = __floats2half2_rn(a0[0], a0[1]);
    __half2 p23 = __floats2half2_rn(a0[2], a0[3]);
    uint2 u;
    u.x = *reinterpret_cast<unsigned int*>(&p01);
    u.y = *reinterpret_cast<unsigned int*>(&p23);
    *reinterpret_cast<uint2*>(Tout + (size_t)rowA * DD + c0) = u;
  }
  if (rowA + 1 < n) {
    __half2 p01 = __floats2half2_rn(a1[0], a1[1]);
    __half2 p23 = __floats2half2_rn(a1[2], a1[3]);
    uint2 u;
    u.x = *reinterpret_cast<unsigned int*>(&p01);
    u.y = *reinterpret_cast<unsigned int*>(&p23);
    *reinterpret_cast<uint2*>(Tout + (size_t)(rowA + 1) * DD + c0) = u;
  }
}

// ---- final CSR aggregation: out[d,:] = dinv[d]*sum T16[c,:] + b (fp32) ----
__global__ __launch_bounds__(256) void aggregate_kernel(
    const __half* __restrict__ T, const int* __restrict__ offs,
    const int* __restrict__ col, const float* __restrict__ dinv,
    const float* __restrict__ bias, float* __restrict__ out, int n) {
  int gid = blockIdx.x * blockDim.x + threadIdx.x;
  int wid = gid >> 6;
  if (wid >= n) return;
  int lane = threadIdx.x & 63;
  int g = lane >> 3;
  int s = lane & 7;
  int j0 = offs[wid], j1 = offs[wid + 1];
  float acc[8];
  gather_node(T + s * 8, col, j0, j1 - j0, lane, g, acc);

  if (g == 0) {
    float dv = dinv[wid];
    const float4* bp = reinterpret_cast<const float4*>(bias + s * 8);
    float4 b0 = bp[0], b1 = bp[1];
    float4 o0, o1;
    o0.x = fmaf(acc[0], dv, b0.x);
    o0.y = fmaf(acc[1], dv, b0.y);
    o0.z = fmaf(acc[2], dv, b0.z);
    o0.w = fmaf(acc[3], dv, b0.w);
    o1.x = fmaf(acc[4], dv, b1.x);
    o1.y = fmaf(acc[5], dv, b1.y);
    o1.z = fmaf(acc[6], dv, b1.z);
    o1.w = fmaf(acc[7], dv, b1.w);
    float4* op = reinterpret_cast<float4*>(out + (size_t)wid * DD + s * 8);
    op[0] = o0;
    op[1] = o1;
  }
}

// ---------------------------------------------------------------------------
extern "C" void kernel_launch(void* const* d_in, const int* in_sizes, int n_in,
                              void* d_out, int out_size, void* d_ws, size_t ws_size,
                              hipStream_t stream) {
  const float* x   = (const float*)d_in[0];
  const void*  eix = d_in[1];
  const float* Win = (const float*)d_in[2];
  const float* bin = (const float*)d_in[3];
  const float* W1  = (const float*)d_in[4];
  const float* b1  = (const float*)d_in[5];
  const float* W2  = (const float*)d_in[6];
  const float* b2  = (const float*)d_in[7];
  const float* W3  = (const float*)d_in[8];
  const float* b3  = (const float*)d_in[9];

  int n = in_sizes[0] / DD;
  int E = in_sizes[1] / 2;
  int M = E + n;
  int chunk = (n + NB - 1) / NB;    // local-dst fits 16 bits for n <= 65536

  char* w = (char*)d_ws;
  auto carve = [&](size_t bytes) {
    char* p = w;
    w += (bytes + 255) & ~(size_t)255;
    return p;
  };
  int*          histPB     = (int*)carve((size_t)GB * NB * 4);
  int*          localpre   = (int*)carve((size_t)NB * GB * 4);
  int*          tot        = (int*)carve((size_t)NB * 4);
  int*          bucketBase = (int*)carve((size_t)(NB + 1) * 4);
  int*          csrBase    = (int*)carve((size_t)NB * 4);
  int*          offs       = (int*)carve((size_t)(n + 1) * 4);
  float*        dinv       = (float*)carve((size_t)n * 4);
  unsigned int* rec        = (unsigned int*)carve((size_t)E * 4);
  int*          col        = (int*)carve((size_t)M * 4);
  __half*       t16a       = (__half*)carve((size_t)n * DD * 2);
  __half*       t16b       = (__half*)carve((size_t)n * DD * 2);

  histA_kernel<<<GB, 256, 0, stream>>>(eix, E, chunk, histPB);
  scanB1_kernel<<<NB, GB, 0, stream>>>(histPB, localpre, tot);
  scanB2_kernel<<<1, NB, 0, stream>>>(tot, bucketBase, csrBase, offs, n, chunk);
  passB_kernel<<<GB, 256, 0, stream>>>(eix, E, chunk, bucketBase, localpre, rec);
  passC_kernel<<<NB, 256, 0, stream>>>(rec, bucketBase, csrBase, offs, dinv,
                                       col, n, chunk);

  int tile_grid = (n + 63) / 64;
  int agg_grid  = (n * 64 + 255) / 256;

  // t16a = (dinv (*) relu(x@Win+bin)) @ W1
  gemm01_kernel<<<tile_grid, 256, 0, stream>>>(x, Win, bin, W1, dinv, t16a, n);
  // conv1 + transform2: t16b = (dinv (*) relu(dinv*agg(t16a)+b1)) @ W2
  agg_gemm_kernel<<<tile_grid, 512, 0, stream>>>(t16a, offs, col, dinv, b1, W2, t16b, n);
  // conv2 + transform3: t16a = (dinv (*) relu(dinv*agg(t16b)+b2)) @ W3
  agg_gemm_kernel<<<tile_grid, 512, 0, stream>>>(t16b, offs, col, dinv, b2, W3, t16a, n);
  // conv3: out = dinv*agg(t16a) + b3
  aggregate_kernel<<<agg_grid, 256, 0, stream>>>(t16a, offs, col, dinv, b3, (float*)d_out, n);
}

// Round 13
// 244.709 us; speedup vs baseline: 1.7711x; 1.7711x over previous
//
#include <hip/hip_runtime.h>
#include <hip/hip_fp16.h>

#define DD 64
#define NB 256          // buckets (one per passC2 block); requires n <= 65536
#define GB 128          // blocks for histA/passB2

// ---------------------------------------------------------------------------
// Inline int64-vs-int32 detection: first 128 odd u32 words all zero <=> int64.
__device__ __forceinline__ int detect_is64(const unsigned int* p, int E,
                                           int tid, int* sflag) {
  if (tid == 0) *sflag = 1;
  __syncthreads();
  int lim = E < 128 ? E : 128;
  if (tid < lim && p[2 * tid + 1] != 0u) *sflag = 0;
  __syncthreads();
  return *sflag;
}

// ---- histA: per-(block,bucket) histogram of dst ---------------------------
__global__ __launch_bounds__(256) void histA_kernel(
    const void* __restrict__ eidx, int E, int chunk,
    int* __restrict__ histPB) {
  __shared__ int h[NB];
  __shared__ int sflag;
  int tid = threadIdx.x;
  int is64 = detect_is64((const unsigned int*)eidx, E, tid, &sflag);
  h[tid] = 0;
  __syncthreads();
  int seg = (E + GB - 1) / GB;
  int e0 = blockIdx.x * seg;
  int e1 = min(e0 + seg, E);
  for (int e = e0 + tid; e < e1; e += 256) {
    int d;
    if (is64) d = (int)((const long long*)eidx)[e + E];
    else      d = ((const int*)eidx)[e + E];
    atomicAdd(&h[d / chunk], 1);
  }
  __syncthreads();
  histPB[blockIdx.x * NB + tid] = h[tid];
}

// ---- passB2: recompute bases from histPB, then bucketed scatter -----------
__global__ __launch_bounds__(256) void passB2_kernel(
    const void* __restrict__ eidx, int E, int chunk,
    const int* __restrict__ histPB, unsigned int* __restrict__ rec) {
  __shared__ int cur[NB];
  __shared__ int sc[NB];
  __shared__ int sflag;
  int tid = threadIdx.x;
  int blk = blockIdx.x;
  int is64 = detect_is64((const unsigned int*)eidx, E, tid, &sflag);

  // bucket tid: total over all source blocks + prefix over blocks < blk
  int tot = 0, pre = 0;
  for (int t = 0; t < GB; ++t) {
    int v = histPB[t * NB + tid];
    tot += v;
    if (t < blk) pre += v;
  }
  sc[tid] = tot;
  __syncthreads();
  for (int off = 1; off < NB; off <<= 1) {
    int t = (tid >= off) ? sc[tid - off] : 0;
    __syncthreads();
    sc[tid] += t;
    __syncthreads();
  }
  cur[tid] = (sc[tid] - tot) + pre;   // bucketBase + local prefix
  __syncthreads();

  int seg = (E + GB - 1) / GB;
  int e0 = blk * seg;
  int e1 = min(e0 + seg, E);
  for (int e = e0 + tid; e < e1; e += 256) {
    int s, d;
    if (is64) {
      const long long* p = (const long long*)eidx;
      s = (int)p[e];
      d = (int)p[e + E];
    } else {
      const int* p = (const int*)eidx;
      s = p[e];
      d = p[e + E];
    }
    int b = d / chunk;
    int ld = d - b * chunk;
    int pos = atomicAdd(&cur[b], 1);
    rec[pos] = ((unsigned int)s << 16) | (unsigned int)ld;
  }
}

// ---- passC2: recompute bases, then per-bucket CSR finalize ----------------
__global__ __launch_bounds__(256) void passC2_kernel(
    const unsigned int* __restrict__ rec, const int* __restrict__ histPB,
    int* __restrict__ offs, float* __restrict__ dinv, int* __restrict__ col,
    int n, int E, int chunk) {
  int b = blockIdx.x;
  int tid = threadIdx.x;
  __shared__ int sc[NB];
  __shared__ int hist[NB];
  __shared__ int cursor[NB];
  __shared__ int jb0s, jb1s;

  // recompute bucket totals + scan -> this bucket's record range
  int tot = 0;
  for (int t = 0; t < GB; ++t) tot += histPB[t * NB + tid];
  sc[tid] = tot;
  __syncthreads();
  for (int off = 1; off < NB; off <<= 1) {
    int t = (tid >= off) ? sc[tid - off] : 0;
    __syncthreads();
    sc[tid] += t;
    __syncthreads();
  }
  if (tid == b) { jb0s = sc[tid] - tot; jb1s = sc[tid]; }
  __syncthreads();
  int jb0 = jb0s, jb1 = jb1s;

  if (b == 0 && tid == 0) offs[n] = E + n;
  int d0 = b * chunk;
  if (d0 >= n) return;
  int nd = min(chunk, n - d0);
  int cb = jb0 + d0;                 // csrBase (d0 < n here)

  hist[tid] = (tid < nd) ? 1 : 0;    // self-loop seed
  __syncthreads();
  for (int j = jb0 + tid; j < jb1; j += 256)
    atomicAdd(&hist[rec[j] & 0xFFFFu], 1);
  __syncthreads();
  int deg = hist[tid];
  sc[tid] = deg;
  __syncthreads();
  for (int off = 1; off < NB; off <<= 1) {
    int t = (tid >= off) ? sc[tid - off] : 0;
    __syncthreads();
    sc[tid] += t;
    __syncthreads();
  }
  int loc = sc[tid] - deg;           // exclusive prefix
  if (tid < nd) {
    offs[d0 + tid] = cb + loc;
    dinv[d0 + tid] = rsqrtf((float)deg);
    col[cb + loc] = d0 + tid;        // self-loop first
  }
  cursor[tid] = loc + 1;
  __syncthreads();
  for (int j = jb0 + tid; j < jb1; j += 256) {
    unsigned int r = rec[j];
    int p = atomicAdd(&cursor[(int)(r & 0xFFFFu)], 1);
    col[cb + p] = (int)(r >> 16);
  }
}

// ---- fused layer0+transform1: T16 = dinv * (relu(x@Win + bin) @ W1) -------
__global__ __launch_bounds__(256) void gemm01_kernel(
    const float* __restrict__ X, const float* __restrict__ Win,
    const float* __restrict__ bin, const float* __restrict__ W1,
    const float* __restrict__ dinv, __half* __restrict__ T16, int n) {
  __shared__ float Ws[64][68];
  __shared__ float Hs[64][68];
  int tid = threadIdx.x;
  int row0 = blockIdx.x * 64;

  for (int i = tid; i < 1024; i += 256) {
    int r = i >> 4, c = (i & 15) << 2;
    *reinterpret_cast<float4*>(&Ws[r][c]) = ((const float4*)Win)[i];
    float4 hv = make_float4(0.f, 0.f, 0.f, 0.f);
    if (row0 + r < n)
      hv = *reinterpret_cast<const float4*>(X + (size_t)(row0 + r) * DD + c);
    *reinterpret_cast<float4*>(&Hs[r][c]) = hv;
  }
  __syncthreads();

  int tr = tid >> 4, tc = tid & 15;
  int r0 = tr << 2, c0 = tc << 2;

  float acc[4][4];
#pragma unroll
  for (int i = 0; i < 4; ++i)
#pragma unroll
    for (int j = 0; j < 4; ++j) acc[i][j] = 0.f;

#pragma unroll
  for (int k = 0; k < 64; ++k) {
    float h0 = Hs[r0 + 0][k], h1 = Hs[r0 + 1][k];
    float h2 = Hs[r0 + 2][k], h3 = Hs[r0 + 3][k];
    float4 wv = *reinterpret_cast<const float4*>(&Ws[k][c0]);
    acc[0][0] = fmaf(h0, wv.x, acc[0][0]); acc[0][1] = fmaf(h0, wv.y, acc[0][1]);
    acc[0][2] = fmaf(h0, wv.z, acc[0][2]); acc[0][3] = fmaf(h0, wv.w, acc[0][3]);
    acc[1][0] = fmaf(h1, wv.x, acc[1][0]); acc[1][1] = fmaf(h1, wv.y, acc[1][1]);
    acc[1][2] = fmaf(h1, wv.z, acc[1][2]); acc[1][3] = fmaf(h1, wv.w, acc[1][3]);
    acc[2][0] = fmaf(h2, wv.x, acc[2][0]); acc[2][1] = fmaf(h2, wv.y, acc[2][1]);
    acc[2][2] = fmaf(h2, wv.z, acc[2][2]); acc[2][3] = fmaf(h2, wv.w, acc[2][3]);
    acc[3][0] = fmaf(h3, wv.x, acc[3][0]); acc[3][1] = fmaf(h3, wv.y, acc[3][1]);
    acc[3][2] = fmaf(h3, wv.z, acc[3][2]); acc[3][3] = fmaf(h3, wv.w, acc[3][3]);
  }

  // h = relu(acc + bin)
  float4 bv = *reinterpret_cast<const float4*>(bin + c0);
#pragma unroll
  for (int i = 0; i < 4; ++i) {
    acc[i][0] = fmaxf(acc[i][0] + bv.x, 0.f);
    acc[i][1] = fmaxf(acc[i][1] + bv.y, 0.f);
    acc[i][2] = fmaxf(acc[i][2] + bv.z, 0.f);
    acc[i][3] = fmaxf(acc[i][3] + bv.w, 0.f);
  }
  __syncthreads();              // everyone done reading Hs/Ws

  // write h tile back into Hs; restage Ws = W1
#pragma unroll
  for (int i = 0; i < 4; ++i)
    *reinterpret_cast<float4*>(&Hs[r0 + i][c0]) =
        make_float4(acc[i][0], acc[i][1], acc[i][2], acc[i][3]);
  for (int i = tid; i < 1024; i += 256) {
    int r = i >> 4, c = (i & 15) << 2;
    *reinterpret_cast<float4*>(&Ws[r][c]) = ((const float4*)W1)[i];
  }
  __syncthreads();

#pragma unroll
  for (int i = 0; i < 4; ++i)
#pragma unroll
    for (int j = 0; j < 4; ++j) acc[i][j] = 0.f;

#pragma unroll
  for (int k = 0; k < 64; ++k) {
    float h0 = Hs[r0 + 0][k], h1 = Hs[r0 + 1][k];
    float h2 = Hs[r0 + 2][k], h3 = Hs[r0 + 3][k];
    float4 wv = *reinterpret_cast<const float4*>(&Ws[k][c0]);
    acc[0][0] = fmaf(h0, wv.x, acc[0][0]); acc[0][1] = fmaf(h0, wv.y, acc[0][1]);
    acc[0][2] = fmaf(h0, wv.z, acc[0][2]); acc[0][3] = fmaf(h0, wv.w, acc[0][3]);
    acc[1][0] = fmaf(h1, wv.x, acc[1][0]); acc[1][1] = fmaf(h1, wv.y, acc[1][1]);
    acc[1][2] = fmaf(h1, wv.z, acc[1][2]); acc[1][3] = fmaf(h1, wv.w, acc[1][3]);
    acc[2][0] = fmaf(h2, wv.x, acc[2][0]); acc[2][1] = fmaf(h2, wv.y, acc[2][1]);
    acc[2][2] = fmaf(h2, wv.z, acc[2][2]); acc[2][3] = fmaf(h2, wv.w, acc[2][3]);
    acc[3][0] = fmaf(h3, wv.x, acc[3][0]); acc[3][1] = fmaf(h3, wv.y, acc[3][1]);
    acc[3][2] = fmaf(h3, wv.z, acc[3][2]); acc[3][3] = fmaf(h3, wv.w, acc[3][3]);
  }

#pragma unroll
  for (int i = 0; i < 4; ++i) {
    long long row = (long long)row0 + r0 + i;
    if (row >= n) break;
    float dv = dinv[row];
    __half2 p01 = __floats2half2_rn(acc[i][0] * dv, acc[i][1] * dv);
    __half2 p23 = __floats2half2_rn(acc[i][2] * dv, acc[i][3] * dv);
    uint2 u;
    u.x = *reinterpret_cast<unsigned int*>(&p01);
    u.y = *reinterpret_cast<unsigned int*>(&p23);
    *reinterpret_cast<uint2*>(T16 + (size_t)row * DD + c0) = u;
  }
}

// ---- dense GEMM: T16 = dinv * (H @ W) -------------------------------------
__global__ __launch_bounds__(256) void gemm_kernel(
    const float* __restrict__ H, const float* __restrict__ W,
    const float* __restrict__ dinv, __half* __restrict__ T16, int n) {
  __shared__ float Ws[64][68];
  __shared__ float Hs[64][68];
  int tid = threadIdx.x;
  int row0 = blockIdx.x * 64;

  for (int i = tid; i < 1024; i += 256) {
    int r = i >> 4, c = (i & 15) << 2;
    *reinterpret_cast<float4*>(&Ws[r][c]) = ((const float4*)W)[i];
    float4 hv = make_float4(0.f, 0.f, 0.f, 0.f);
    if (row0 + r < n)
      hv = *reinterpret_cast<const float4*>(H + (size_t)(row0 + r) * DD + c);
    *reinterpret_cast<float4*>(&Hs[r][c]) = hv;
  }
  __syncthreads();

  int tr = tid >> 4, tc = tid & 15;
  int r0 = tr << 2, c0 = tc << 2;

  float acc[4][4];
#pragma unroll
  for (int i = 0; i < 4; ++i)
#pragma unroll
    for (int j = 0; j < 4; ++j) acc[i][j] = 0.f;

#pragma unroll
  for (int k = 0; k < 64; ++k) {
    float h0 = Hs[r0 + 0][k], h1 = Hs[r0 + 1][k];
    float h2 = Hs[r0 + 2][k], h3 = Hs[r0 + 3][k];
    float4 wv = *reinterpret_cast<const float4*>(&Ws[k][c0]);
    acc[0][0] = fmaf(h0, wv.x, acc[0][0]); acc[0][1] = fmaf(h0, wv.y, acc[0][1]);
    acc[0][2] = fmaf(h0, wv.z, acc[0][2]); acc[0][3] = fmaf(h0, wv.w, acc[0][3]);
    acc[1][0] = fmaf(h1, wv.x, acc[1][0]); acc[1][1] = fmaf(h1, wv.y, acc[1][1]);
    acc[1][2] = fmaf(h1, wv.z, acc[1][2]); acc[1][3] = fmaf(h1, wv.w, acc[1][3]);
    acc[2][0] = fmaf(h2, wv.x, acc[2][0]); acc[2][1] = fmaf(h2, wv.y, acc[2][1]);
    acc[2][2] = fmaf(h2, wv.z, acc[2][2]); acc[2][3] = fmaf(h2, wv.w, acc[2][3]);
    acc[3][0] = fmaf(h3, wv.x, acc[3][0]); acc[3][1] = fmaf(h3, wv.y, acc[3][1]);
    acc[3][2] = fmaf(h3, wv.z, acc[3][2]); acc[3][3] = fmaf(h3, wv.w, acc[3][3]);
  }

#pragma unroll
  for (int i = 0; i < 4; ++i) {
    long long row = (long long)row0 + r0 + i;
    if (row >= n) break;
    float dv = dinv[row];
    __half2 p01 = __floats2half2_rn(acc[i][0] * dv, acc[i][1] * dv);
    __half2 p23 = __floats2half2_rn(acc[i][2] * dv, acc[i][3] * dv);
    uint2 u;
    u.x = *reinterpret_cast<unsigned int*>(&p01);
    u.y = *reinterpret_cast<unsigned int*>(&p23);
    *reinterpret_cast<uint2*>(T16 + (size_t)row * DD + c0) = u;
  }
}

// ---- CSR aggregation: out[d,:] = dinv[d] * sum_{c in N(d)} T16[c,:] + b ---
// one wave per node; lane = (row-group g = lane>>3, dim-slice s = lane&7).
// Wave-cooperative col preload, shfl index distribution, 4-deep row gathers.
__device__ __forceinline__ void acc8(float* acc, uint4 u) {
  __half2 h0 = *reinterpret_cast<__half2*>(&u.x);
  __half2 h1 = *reinterpret_cast<__half2*>(&u.y);
  __half2 h2 = *reinterpret_cast<__half2*>(&u.z);
  __half2 h3 = *reinterpret_cast<__half2*>(&u.w);
  float2 f0 = __half22float2(h0);
  float2 f1 = __half22float2(h1);
  float2 f2 = __half22float2(h2);
  float2 f3 = __half22float2(h3);
  acc[0] += f0.x; acc[1] += f0.y;
  acc[2] += f1.x; acc[3] += f1.y;
  acc[4] += f2.x; acc[5] += f2.y;
  acc[6] += f3.x; acc[7] += f3.y;
}

__global__ __launch_bounds__(256) void aggregate_kernel(
    const __half* __restrict__ T, const int* __restrict__ offs,
    const int* __restrict__ col, const float* __restrict__ dinv,
    const float* __restrict__ bias, float* __restrict__ out,
    int n, int relu) {
  int gid = blockIdx.x * blockDim.x + threadIdx.x;
  int wid = gid >> 6;
  if (wid >= n) return;
  int lane = threadIdx.x & 63;
  int g = lane >> 3;          // row group 0..7
  int s = lane & 7;           // dim slice: dims 8s..8s+7
  int j0 = offs[wid], j1 = offs[wid + 1];
  int deg = j1 - j0;
  const __half* Ts = T + s * 8;

  float acc[8];
#pragma unroll
  for (int k = 0; k < 8; ++k) acc[k] = 0.f;

  for (int base = 0; base < deg; base += 64) {
    int idx = base + lane;
    int c_local = (idx < deg) ? col[j0 + idx] : -1;
    int rem = deg - base; if (rem > 64) rem = 64;
    int nr = (rem + 7) >> 3;          // rounds in this batch (wave-uniform)
    int t = 0;
    for (; t + 4 <= nr; t += 4) {     // 4 rounds in flight
      int i = t * 8 + g;
      int c0 = __shfl(c_local, i, 64);
      int c1 = __shfl(c_local, i + 8, 64);
      int c2 = __shfl(c_local, i + 16, 64);
      int c3 = __shfl(c_local, i + 24, 64);
      uint4 u0 = *reinterpret_cast<const uint4*>(Ts + (size_t)c0 * DD);
      uint4 u1 = *reinterpret_cast<const uint4*>(Ts + (size_t)c1 * DD);
      uint4 u2 = *reinterpret_cast<const uint4*>(Ts + (size_t)c2 * DD);
      if (c3 >= 0) {
        uint4 u3 = *reinterpret_cast<const uint4*>(Ts + (size_t)c3 * DD);
        acc8(acc, u3);
      }
      acc8(acc, u0);
      acc8(acc, u1);
      acc8(acc, u2);
    }
    for (; t < nr; ++t) {             // leftover rounds (masked)
      int i = t * 8 + g;
      int c = __shfl(c_local, i, 64);
      if (c >= 0) {
        uint4 u = *reinterpret_cast<const uint4*>(Ts + (size_t)c * DD);
        acc8(acc, u);
      }
    }
  }

  // reduce over g (lane bits 3,4,5)
#pragma unroll
  for (int m = 8; m <= 32; m <<= 1) {
#pragma unroll
    for (int k = 0; k < 8; ++k)
      acc[k] += __shfl_xor(acc[k], m, 64);
  }

  if (g == 0) {
    float dv = dinv[wid];
    const float4* bp = reinterpret_cast<const float4*>(bias + s * 8);
    float4 b0 = bp[0], b1 = bp[1];
    float4 o0, o1;
    o0.x = fmaf(acc[0], dv, b0.x);
    o0.y = fmaf(acc[1], dv, b0.y);
    o0.z = fmaf(acc[2], dv, b0.z);
    o0.w = fmaf(acc[3], dv, b0.w);
    o1.x = fmaf(acc[4], dv, b1.x);
    o1.y = fmaf(acc[5], dv, b1.y);
    o1.z = fmaf(acc[6], dv, b1.z);
    o1.w = fmaf(acc[7], dv, b1.w);
    if (relu) {
      o0.x = fmaxf(o0.x, 0.f); o0.y = fmaxf(o0.y, 0.f);
      o0.z = fmaxf(o0.z, 0.f); o0.w = fmaxf(o0.w, 0.f);
      o1.x = fmaxf(o1.x, 0.f); o1.y = fmaxf(o1.y, 0.f);
      o1.z = fmaxf(o1.z, 0.f); o1.w = fmaxf(o1.w, 0.f);
    }
    float4* op = reinterpret_cast<float4*>(out + (size_t)wid * DD + s * 8);
    op[0] = o0;
    op[1] = o1;
  }
}

// ---------------------------------------------------------------------------
extern "C" void kernel_launch(void* const* d_in, const int* in_sizes, int n_in,
                              void* d_out, int out_size, void* d_ws, size_t ws_size,
                              hipStream_t stream) {
  const float* x   = (const float*)d_in[0];
  const void*  eix = d_in[1];
  const float* Win = (const float*)d_in[2];
  const float* bin = (const float*)d_in[3];
  const float* W1  = (const float*)d_in[4];
  const float* b1  = (const float*)d_in[5];
  const float* W2  = (const float*)d_in[6];
  const float* b2  = (const float*)d_in[7];
  const float* W3  = (const float*)d_in[8];
  const float* b3  = (const float*)d_in[9];

  int n = in_sizes[0] / DD;
  int E = in_sizes[1] / 2;
  int M = E + n;
  int chunk = (n + NB - 1) / NB;    // local-dst fits 16 bits for n <= 65536

  char* w = (char*)d_ws;
  auto carve = [&](size_t bytes) {
    char* p = w;
    w += (bytes + 255) & ~(size_t)255;
    return p;
  };
  int*          histPB = (int*)carve((size_t)GB * NB * 4);
  int*          offs   = (int*)carve((size_t)(n + 1) * 4);
  float*        dinv   = (float*)carve((size_t)n * 4);
  unsigned int* rec    = (unsigned int*)carve((size_t)E * 4);
  int*          col    = (int*)carve((size_t)M * 4);
  float*        hbuf   = (float*)carve((size_t)n * DD * 4);
  __half*       t16    = (__half*)carve((size_t)n * DD * 2);

  histA_kernel<<<GB, 256, 0, stream>>>(eix, E, chunk, histPB);
  passB2_kernel<<<GB, 256, 0, stream>>>(eix, E, chunk, histPB, rec);
  passC2_kernel<<<NB, 256, 0, stream>>>(rec, histPB, offs, dinv, col, n, E, chunk);

  int tile_grid = (n + 63) / 64;
  int agg_grid  = (n * 64 + 255) / 256;

  // t16 = (dinv (*) relu(x@Win+bin)) @ W1   (fused, verified)
  gemm01_kernel<<<tile_grid, 256, 0, stream>>>(x, Win, bin, W1, dinv, t16, n);
  // conv1: hbuf = relu(dinv*agg(t16) + b1)
  aggregate_kernel<<<agg_grid, 256, 0, stream>>>(t16, offs, col, dinv, b1, hbuf, n, 1);
  // conv2 transform + aggregate
  gemm_kernel<<<tile_grid, 256, 0, stream>>>(hbuf, W2, dinv, t16, n);
  aggregate_kernel<<<agg_grid, 256, 0, stream>>>(t16, offs, col, dinv, b2, hbuf, n, 1);
  // conv3 transform + aggregate (no relu, fp32 out)
  gemm_kernel<<<tile_grid, 256, 0, stream>>>(hbuf, W3, dinv, t16, n);
  aggregate_kernel<<<agg_grid, 256, 0, stream>>>(t16, offs, col, dinv, b3, (float*)d_out, n, 0);
}

// Round 14
// 210.193 us; speedup vs baseline: 2.0620x; 1.1642x over previous
//
#include <hip/hip_runtime.h>
#include <hip/hip_fp16.h>

#define DD 64
#define NB 256          // buckets (one per passC2 block); requires n <= 65536
#define GB 128          // blocks for histA/passB2

// ---------------------------------------------------------------------------
// Inline int64-vs-int32 detection: first 128 odd u32 words all zero <=> int64.
__device__ __forceinline__ int detect_is64(const unsigned int* p, int E,
                                           int tid, int* sflag) {
  if (tid == 0) *sflag = 1;
  __syncthreads();
  int lim = E < 128 ? E : 128;
  if (tid < lim && p[2 * tid + 1] != 0u) *sflag = 0;
  __syncthreads();
  return *sflag;
}

// ---- histA: per-(block,bucket) histogram of dst ---------------------------
__global__ __launch_bounds__(256) void histA_kernel(
    const void* __restrict__ eidx, int E, int chunk,
    int* __restrict__ histPB) {
  __shared__ int h[NB];
  __shared__ int sflag;
  int tid = threadIdx.x;
  int is64 = detect_is64((const unsigned int*)eidx, E, tid, &sflag);
  h[tid] = 0;
  __syncthreads();
  int seg = (E + GB - 1) / GB;
  int e0 = blockIdx.x * seg;
  int e1 = min(e0 + seg, E);
  for (int e = e0 + tid; e < e1; e += 256) {
    int d;
    if (is64) d = (int)((const long long*)eidx)[e + E];
    else      d = ((const int*)eidx)[e + E];
    atomicAdd(&h[d / chunk], 1);
  }
  __syncthreads();
  histPB[blockIdx.x * NB + tid] = h[tid];
}

// ---- passB2: recompute bases from histPB, then bucketed scatter -----------
__global__ __launch_bounds__(256) void passB2_kernel(
    const void* __restrict__ eidx, int E, int chunk,
    const int* __restrict__ histPB, unsigned int* __restrict__ rec) {
  __shared__ int cur[NB];
  __shared__ int sc[NB];
  __shared__ int sflag;
  int tid = threadIdx.x;
  int blk = blockIdx.x;
  int is64 = detect_is64((const unsigned int*)eidx, E, tid, &sflag);

  // bucket tid: total over all source blocks + prefix over blocks < blk
  int tot = 0, pre = 0;
  for (int t = 0; t < GB; ++t) {
    int v = histPB[t * NB + tid];
    tot += v;
    if (t < blk) pre += v;
  }
  sc[tid] = tot;
  __syncthreads();
  for (int off = 1; off < NB; off <<= 1) {
    int t = (tid >= off) ? sc[tid - off] : 0;
    __syncthreads();
    sc[tid] += t;
    __syncthreads();
  }
  cur[tid] = (sc[tid] - tot) + pre;   // bucketBase + local prefix
  __syncthreads();

  int seg = (E + GB - 1) / GB;
  int e0 = blk * seg;
  int e1 = min(e0 + seg, E);
  for (int e = e0 + tid; e < e1; e += 256) {
    int s, d;
    if (is64) {
      const long long* p = (const long long*)eidx;
      s = (int)p[e];
      d = (int)p[e + E];
    } else {
      const int* p = (const int*)eidx;
      s = p[e];
      d = p[e + E];
    }
    int b = d / chunk;
    int ld = d - b * chunk;
    int pos = atomicAdd(&cur[b], 1);
    rec[pos] = ((unsigned int)s << 16) | (unsigned int)ld;
  }
}

// ---- passC2: recompute bases, then per-bucket CSR finalize ----------------
__global__ __launch_bounds__(256) void passC2_kernel(
    const unsigned int* __restrict__ rec, const int* __restrict__ histPB,
    int* __restrict__ offs, float* __restrict__ dinv, int* __restrict__ col,
    int n, int E, int chunk) {
  int b = blockIdx.x;
  int tid = threadIdx.x;
  __shared__ int sc[NB];
  __shared__ int hist[NB];
  __shared__ int cursor[NB];
  __shared__ int jb0s, jb1s;

  // recompute bucket totals + scan -> this bucket's record range
  int tot = 0;
  for (int t = 0; t < GB; ++t) tot += histPB[t * NB + tid];
  sc[tid] = tot;
  __syncthreads();
  for (int off = 1; off < NB; off <<= 1) {
    int t = (tid >= off) ? sc[tid - off] : 0;
    __syncthreads();
    sc[tid] += t;
    __syncthreads();
  }
  if (tid == b) { jb0s = sc[tid] - tot; jb1s = sc[tid]; }
  __syncthreads();
  int jb0 = jb0s, jb1 = jb1s;

  if (b == 0 && tid == 0) offs[n] = E + n;
  int d0 = b * chunk;
  if (d0 >= n) return;
  int nd = min(chunk, n - d0);
  int cb = jb0 + d0;                 // csrBase (d0 < n here)

  hist[tid] = (tid < nd) ? 1 : 0;    // self-loop seed
  __syncthreads();
  for (int j = jb0 + tid; j < jb1; j += 256)
    atomicAdd(&hist[rec[j] & 0xFFFFu], 1);
  __syncthreads();
  int deg = hist[tid];
  sc[tid] = deg;
  __syncthreads();
  for (int off = 1; off < NB; off <<= 1) {
    int t = (tid >= off) ? sc[tid - off] : 0;
    __syncthreads();
    sc[tid] += t;
    __syncthreads();
  }
  int loc = sc[tid] - deg;           // exclusive prefix
  if (tid < nd) {
    offs[d0 + tid] = cb + loc;
    dinv[d0 + tid] = rsqrtf((float)deg);
    col[cb + loc] = d0 + tid;        // self-loop first
  }
  cursor[tid] = loc + 1;
  __syncthreads();
  for (int j = jb0 + tid; j < jb1; j += 256) {
    unsigned int r = rec[j];
    int p = atomicAdd(&cursor[(int)(r & 0xFFFFu)], 1);
    col[cb + p] = (int)(r >> 16);
  }
}

// ---- dense GEMM: acc = H @ W; epilogue: bias+relu -> fp32, or dinv -> fp16 -
__global__ __launch_bounds__(256) void gemm_kernel(
    const float* __restrict__ H, const float* __restrict__ W,
    const float* __restrict__ bias, const float* __restrict__ dinv,
    float* __restrict__ T32, __half* __restrict__ T16, int n) {
  __shared__ float Ws[64][68];
  __shared__ float Hs[64][68];
  int tid = threadIdx.x;
  int row0 = blockIdx.x * 64;

  for (int i = tid; i < 1024; i += 256) {
    int r = i >> 4, c = (i & 15) << 2;
    *reinterpret_cast<float4*>(&Ws[r][c]) = ((const float4*)W)[i];
    float4 hv = make_float4(0.f, 0.f, 0.f, 0.f);
    if (row0 + r < n)
      hv = *reinterpret_cast<const float4*>(H + (size_t)(row0 + r) * DD + c);
    *reinterpret_cast<float4*>(&Hs[r][c]) = hv;
  }
  __syncthreads();

  int tr = tid >> 4, tc = tid & 15;
  int r0 = tr << 2, c0 = tc << 2;

  float acc[4][4];
#pragma unroll
  for (int i = 0; i < 4; ++i)
#pragma unroll
    for (int j = 0; j < 4; ++j) acc[i][j] = 0.f;

#pragma unroll
  for (int k = 0; k < 64; ++k) {
    float h0 = Hs[r0 + 0][k], h1 = Hs[r0 + 1][k];
    float h2 = Hs[r0 + 2][k], h3 = Hs[r0 + 3][k];
    float4 wv = *reinterpret_cast<const float4*>(&Ws[k][c0]);
    acc[0][0] = fmaf(h0, wv.x, acc[0][0]); acc[0][1] = fmaf(h0, wv.y, acc[0][1]);
    acc[0][2] = fmaf(h0, wv.z, acc[0][2]); acc[0][3] = fmaf(h0, wv.w, acc[0][3]);
    acc[1][0] = fmaf(h1, wv.x, acc[1][0]); acc[1][1] = fmaf(h1, wv.y, acc[1][1]);
    acc[1][2] = fmaf(h1, wv.z, acc[1][2]); acc[1][3] = fmaf(h1, wv.w, acc[1][3]);
    acc[2][0] = fmaf(h2, wv.x, acc[2][0]); acc[2][1] = fmaf(h2, wv.y, acc[2][1]);
    acc[2][2] = fmaf(h2, wv.z, acc[2][2]); acc[2][3] = fmaf(h2, wv.w, acc[2][3]);
    acc[3][0] = fmaf(h3, wv.x, acc[3][0]); acc[3][1] = fmaf(h3, wv.y, acc[3][1]);
    acc[3][2] = fmaf(h3, wv.z, acc[3][2]); acc[3][3] = fmaf(h3, wv.w, acc[3][3]);
  }

  if (T16) {
    // fp16 path: o = dinv[row] * acc
#pragma unroll
    for (int i = 0; i < 4; ++i) {
      long long row = (long long)row0 + r0 + i;
      if (row >= n) break;
      float dv = dinv[row];
      __half2 p01 = __floats2half2_rn(acc[i][0] * dv, acc[i][1] * dv);
      __half2 p23 = __floats2half2_rn(acc[i][2] * dv, acc[i][3] * dv);
      uint2 u;
      u.x = *reinterpret_cast<unsigned int*>(&p01);
      u.y = *reinterpret_cast<unsigned int*>(&p23);
      *reinterpret_cast<uint2*>(T16 + (size_t)row * DD + c0) = u;
    }
  } else {
    // fp32 path: o = relu(acc + bias)
    float4 bv = *reinterpret_cast<const float4*>(bias + c0);
#pragma unroll
    for (int i = 0; i < 4; ++i) {
      long long row = (long long)row0 + r0 + i;
      if (row >= n) break;
      float4 o;
      o.x = fmaxf(acc[i][0] + bv.x, 0.f);
      o.y = fmaxf(acc[i][1] + bv.y, 0.f);
      o.z = fmaxf(acc[i][2] + bv.z, 0.f);
      o.w = fmaxf(acc[i][3] + bv.w, 0.f);
      *reinterpret_cast<float4*>(T32 + (size_t)row * DD + c0) = o;
    }
  }
}

// ---- CSR aggregation: out[d,:] = dinv[d] * sum_{c in N(d)} T16[c,:] + b ---
// one wave per node; lane = (row-group g = lane>>3, dim-slice s = lane&7).
// Wave-cooperative col preload, shfl index distribution, 8-deep masked
// row gathers (all rounds of a 64-batch issued before accumulation).
__device__ __forceinline__ void acc8(float* acc, uint4 u) {
  __half2 h0 = *reinterpret_cast<__half2*>(&u.x);
  __half2 h1 = *reinterpret_cast<__half2*>(&u.y);
  __half2 h2 = *reinterpret_cast<__half2*>(&u.z);
  __half2 h3 = *reinterpret_cast<__half2*>(&u.w);
  float2 f0 = __half22float2(h0);
  float2 f1 = __half22float2(h1);
  float2 f2 = __half22float2(h2);
  float2 f3 = __half22float2(h3);
  acc[0] += f0.x; acc[1] += f0.y;
  acc[2] += f1.x; acc[3] += f1.y;
  acc[4] += f2.x; acc[5] += f2.y;
  acc[6] += f3.x; acc[7] += f3.y;
}

__global__ __launch_bounds__(256) void aggregate_kernel(
    const __half* __restrict__ T, const int* __restrict__ offs,
    const int* __restrict__ col, const float* __restrict__ dinv,
    const float* __restrict__ bias, float* __restrict__ out,
    int n, int relu) {
  int gid = blockIdx.x * blockDim.x + threadIdx.x;
  int wid = gid >> 6;
  if (wid >= n) return;
  int lane = threadIdx.x & 63;
  int g = lane >> 3;          // row group 0..7
  int s = lane & 7;           // dim slice: dims 8s..8s+7
  int j0 = offs[wid], j1 = offs[wid + 1];
  int deg = j1 - j0;
  const __half* Ts = T + s * 8;

  float acc[8];
#pragma unroll
  for (int k = 0; k < 8; ++k) acc[k] = 0.f;

  for (int base = 0; base < deg; base += 64) {
    int idx = base + lane;
    int c_local = (idx < deg) ? col[j0 + idx] : -1;
    int rem = deg - base; if (rem > 64) rem = 64;
    int nr = (rem + 7) >> 3;          // rounds in this batch (wave-uniform)

    int cc[8];
#pragma unroll
    for (int t = 0; t < 8; ++t)
      cc[t] = (t < nr) ? __shfl(c_local, t * 8 + g, 64) : -1;

    uint4 u[8];
#pragma unroll
    for (int t = 0; t < 8; ++t)
      if (cc[t] >= 0)
        u[t] = *reinterpret_cast<const uint4*>(Ts + (size_t)cc[t] * DD);

#pragma unroll
    for (int t = 0; t < 8; ++t)
      if (cc[t] >= 0) acc8(acc, u[t]);
  }

  // reduce over g (lane bits 3,4,5)
#pragma unroll
  for (int m = 8; m <= 32; m <<= 1) {
#pragma unroll
    for (int k = 0; k < 8; ++k)
      acc[k] += __shfl_xor(acc[k], m, 64);
  }

  if (g == 0) {
    float dv = dinv[wid];
    const float4* bp = reinterpret_cast<const float4*>(bias + s * 8);
    float4 b0 = bp[0], b1 = bp[1];
    float4 o0, o1;
    o0.x = fmaf(acc[0], dv, b0.x);
    o0.y = fmaf(acc[1], dv, b0.y);
    o0.z = fmaf(acc[2], dv, b0.z);
    o0.w = fmaf(acc[3], dv, b0.w);
    o1.x = fmaf(acc[4], dv, b1.x);
    o1.y = fmaf(acc[5], dv, b1.y);
    o1.z = fmaf(acc[6], dv, b1.z);
    o1.w = fmaf(acc[7], dv, b1.w);
    if (relu) {
      o0.x = fmaxf(o0.x, 0.f); o0.y = fmaxf(o0.y, 0.f);
      o0.z = fmaxf(o0.z, 0.f); o0.w = fmaxf(o0.w, 0.f);
      o1.x = fmaxf(o1.x, 0.f); o1.y = fmaxf(o1.y, 0.f);
      o1.z = fmaxf(o1.z, 0.f); o1.w = fmaxf(o1.w, 0.f);
    }
    float4* op = reinterpret_cast<float4*>(out + (size_t)wid * DD + s * 8);
    op[0] = o0;
    op[1] = o1;
  }
}

// ---------------------------------------------------------------------------
extern "C" void kernel_launch(void* const* d_in, const int* in_sizes, int n_in,
                              void* d_out, int out_size, void* d_ws, size_t ws_size,
                              hipStream_t stream) {
  const float* x   = (const float*)d_in[0];
  const void*  eix = d_in[1];
  const float* Win = (const float*)d_in[2];
  const float* bin = (const float*)d_in[3];
  const float* W1  = (const float*)d_in[4];
  const float* b1  = (const float*)d_in[5];
  const float* W2  = (const float*)d_in[6];
  const float* b2  = (const float*)d_in[7];
  const float* W3  = (const float*)d_in[8];
  const float* b3  = (const float*)d_in[9];

  int n = in_sizes[0] / DD;
  int E = in_sizes[1] / 2;
  int M = E + n;
  int chunk = (n + NB - 1) / NB;    // local-dst fits 16 bits for n <= 65536

  char* w = (char*)d_ws;
  auto carve = [&](size_t bytes) {
    char* p = w;
    w += (bytes + 255) & ~(size_t)255;
    return p;
  };
  int*          histPB = (int*)carve((size_t)GB * NB * 4);
  int*          offs   = (int*)carve((size_t)(n + 1) * 4);
  float*        dinv   = (float*)carve((size_t)n * 4);
  unsigned int* rec    = (unsigned int*)carve((size_t)E * 4);
  int*          col    = (int*)carve((size_t)M * 4);
  float*        hbuf   = (float*)carve((size_t)n * DD * 4);
  __half*       t16    = (__half*)carve((size_t)n * DD * 2);

  histA_kernel<<<GB, 256, 0, stream>>>(eix, E, chunk, histPB);
  passB2_kernel<<<GB, 256, 0, stream>>>(eix, E, chunk, histPB, rec);
  passC2_kernel<<<NB, 256, 0, stream>>>(rec, histPB, offs, dinv, col, n, E, chunk);

  int tile_grid = (n + 63) / 64;
  int agg_grid  = (n * 64 + 255) / 256;

  // layer 0: hbuf = relu(x @ Win + bin)          (fp32)
  gemm_kernel<<<tile_grid, 256, 0, stream>>>(x, Win, bin, nullptr, hbuf, nullptr, n);
  // conv1 transform: t16 = dinv * (hbuf @ W1)    (fp16)
  gemm_kernel<<<tile_grid, 256, 0, stream>>>(hbuf, W1, nullptr, dinv, nullptr, t16, n);
  aggregate_kernel<<<agg_grid, 256, 0, stream>>>(t16, offs, col, dinv, b1, hbuf, n, 1);
  // conv2
  gemm_kernel<<<tile_grid, 256, 0, stream>>>(hbuf, W2, nullptr, dinv, nullptr, t16, n);
  aggregate_kernel<<<agg_grid, 256, 0, stream>>>(t16, offs, col, dinv, b2, hbuf, n, 1);
  // conv3 (no relu, fp32 out)
  gemm_kernel<<<tile_grid, 256, 0, stream>>>(hbuf, W3, nullptr, dinv, nullptr, t16, n);
  aggregate_kernel<<<agg_grid, 256, 0, stream>>>(t16, offs, col, dinv, b3, (float*)d_out, n, 0);
}